// Round 4
// baseline (99.743 us; speedup 1.0000x reference)
//
#include <hip/hip_runtime.h>
#include <hip/hip_bf16.h>

typedef __attribute__((ext_vector_type(4)))  float f32x4;
typedef __attribute__((ext_vector_type(16))) float f32x16;
typedef __attribute__((ext_vector_type(8)))  short s16x8;
typedef unsigned short u16;
typedef unsigned int u32;

#define ALPHA 1.6986436f          /* sqrt(2*log2(e)) : dot(a*h, a*h) = sim*log2e */
#define LN2F  0.69314718056f
#define COFF  128.0f              /* static log2-domain offset for softmax */

__device__ __forceinline__ u16 f2bf(float x) {
  union { float f; u32 u; } v; v.f = x;
  u32 r = v.u + 0x7fffu + ((v.u >> 16) & 1u);
  return (u16)(r >> 16);
}

#if __has_builtin(__builtin_amdgcn_exp2f)
__device__ __forceinline__ float fexp2(float x) { return __builtin_amdgcn_exp2f(x); }
#else
__device__ __forceinline__ float fexp2(float x) { return exp2f(x); }
#endif
#if __has_builtin(__builtin_amdgcn_logf)
__device__ __forceinline__ float flog2(float x) { return __builtin_amdgcn_logf(x); }
#else
__device__ __forceinline__ float flog2(float x) { return log2f(x); }
#endif

// 8x fp32 -> packed bf16 (RNE) in 4 instructions
__device__ __forceinline__ s16x8 cvt8(float4 a, float4 b) {
  union { u32 w[4]; s16x8 v; } u;
  asm("v_cvt_pk_bf16_f32 %0, %1, %2" : "=v"(u.w[0]) : "v"(a.x), "v"(a.y));
  asm("v_cvt_pk_bf16_f32 %0, %1, %2" : "=v"(u.w[1]) : "v"(a.z), "v"(a.w));
  asm("v_cvt_pk_bf16_f32 %0, %1, %2" : "=v"(u.w[2]) : "v"(b.x), "v"(b.y));
  asm("v_cvt_pk_bf16_f32 %0, %1, %2" : "=v"(u.w[3]) : "v"(b.z), "v"(b.w));
  return u.v;
}

__device__ __forceinline__ f32x16 mfma32(s16x8 a, s16x8 b, f32x16 c) {
  return __builtin_amdgcn_mfma_f32_32x32x16_bf16(a, b, c, 0, 0, 0);
}
__device__ __forceinline__ f32x16 zero16() {
  f32x16 z;
#pragma unroll
  for (int i = 0; i < 16; ++i) z[i] = 0.f;
  return z;
}
__device__ __forceinline__ void gl16(const void* g, void* l) {
  __builtin_amdgcn_global_load_lds(
      (const __attribute__((address_space(1))) u32*)g,
      (__attribute__((address_space(3))) u32*)l, 16, 0, 0);
}

// =================== prep (fused): hbf + pos4 | axG/axN | nsub ===============
// hbf row r: byte off = r*256 + ((2k) ^ ((r&7)<<4)), bf16 scaled by ALPHA.
// axG[kc][d][32B]: bf16(all_x[kc*16+kk][d]) at byte kc*4096 + d*32 + kk*2.
// axN[kc][row][32B]: row0 = bf16(nall[kc*16+kk]), row1 = 1.0, rows 2..31 = 0.
__global__ __launch_bounds__(256)
void prep_all(const float* __restrict__ h_i, const float* __restrict__ h_j,
              const float* __restrict__ all_x, const float* __restrict__ subx,
              u16* __restrict__ hbf, u16* __restrict__ axG, u16* __restrict__ axN,
              float* __restrict__ nsub, float* __restrict__ pos4) {
  __shared__ float tile[64 * 132];
  __shared__ float nals[64];
  int bid = blockIdx.x, tid = threadIdx.x;
  if (bid < 512) {
    // ---- hbf + pos4 ----
    int t = bid * 256 + tid;
    int row = t >> 4, kb = t & 15;
    const float* src = (row < 4096 ? h_i + (size_t)row * 128
                                   : h_j + (size_t)(row - 4096) * 128) + kb * 8;
    float4 f0 = *(const float4*)(src);
    float4 f1 = *(const float4*)(src + 4);
    float4 sa = {ALPHA * f0.x, ALPHA * f0.y, ALPHA * f0.z, ALPHA * f0.w};
    float4 sb = {ALPHA * f1.x, ALPHA * f1.y, ALPHA * f1.z, ALPHA * f1.w};
    s16x8 o = cvt8(sa, sb);
    char* dst = (char*)hbf + (size_t)row * 256 + ((kb * 16) ^ ((row & 7) << 4));
    *(s16x8*)dst = o;
    if (row < 4096) {   // fp32-exact positives
      const float* srcj = h_j + (size_t)row * 128 + kb * 8;
      float4 g0 = *(const float4*)(srcj);
      float4 g1 = *(const float4*)(srcj + 4);
      float dp = f0.x * g0.x + f0.y * g0.y + f0.z * g0.z + f0.w * g0.w
               + f1.x * g1.x + f1.y * g1.y + f1.z * g1.z + f1.w * g1.w;
      dp += __shfl_xor(dp, 1, 64);
      dp += __shfl_xor(dp, 2, 64);
      dp += __shfl_xor(dp, 4, 64);
      dp += __shfl_xor(dp, 8, 64);
      if ((tid & 15) == 0) pos4[row] = 2.0f * dp;
    }
  } else if (bid < 640) {
    // ---- axG + axN (64 k rows of all_x per block) ----
    int ab = bid - 512;           // 0..127
    int k0 = ab * 64;
#pragma unroll
    for (int j = 0; j < 8; ++j) {
      int idx = (j * 256 + tid) * 4;
      int kk = idx >> 7, d = idx & 127;
      *(float4*)&tile[kk * 132 + d] = *(const float4*)&all_x[(size_t)(k0 + kk) * 128 + d];
    }
    __syncthreads();
    {
      int kk = tid >> 2, q = tid & 3;
      float s = 0.f;
#pragma unroll
      for (int dd = 0; dd < 32; ++dd) { float v = tile[kk * 132 + q * 32 + dd]; s += v * v; }
      s += __shfl_xor(s, 1, 64);
      s += __shfl_xor(s, 2, 64);
      if (q == 0) nals[kk] = s;
    }
    __syncthreads();
#pragma unroll
    for (int half = 0; half < 2; ++half) {
      int tgt = half * 256 + tid;
      int f = tgt >> 7, d = tgt & 127;    // kc-local f in 0..3
      int kc = ab * 4 + f;
      u16* dp = axG + (size_t)kc * 2048 + d * 16;
      s16x8 o0, o1;
#pragma unroll
      for (int kk = 0; kk < 8; ++kk) {
        o0[kk] = (short)f2bf(tile[(f * 16 + kk) * 132 + d]);
        o1[kk] = (short)f2bf(tile[(f * 16 + 8 + kk) * 132 + d]);
      }
      ((s16x8*)dp)[0] = o0; ((s16x8*)dp)[1] = o1;
    }
    if (tid < 128) {
      int f = tid >> 5, row = tid & 31;
      int kc = ab * 4 + f;
      u16* dp = axN + (size_t)kc * 512 + row * 16;
      s16x8 o0, o1;
#pragma unroll
      for (int kk = 0; kk < 8; ++kk) {
        u16 v0 = 0, v1 = 0;
        if (row == 0) { v0 = f2bf(nals[f * 16 + kk]); v1 = f2bf(nals[f * 16 + 8 + kk]); }
        else if (row == 1) { v0 = 0x3F80; v1 = 0x3F80; }
        o0[kk] = (short)v0; o1[kk] = (short)v1;
      }
      ((s16x8*)dp)[0] = o0; ((s16x8*)dp)[1] = o1;
    }
  } else {
    // ---- nsub ----
    int i = (bid - 640) * 256 + tid;
    const float* p = subx + (size_t)i * 128;
    float s = 0.f;
#pragma unroll
    for (int c = 0; c < 32; ++c) {
      float4 v = ((const float4*)p)[c];
      s += v.x * v.x + v.y * v.y + v.z * v.z + v.w * v.w;
    }
    nsub[i] = s;
  }
}

// =================== main (fused): graph + contrast ==========================
// bid%3 < 2 -> graph (1024 blocks): gid=(bid/3)*2+(bid%3); mt=gid>>5 (128 rows),
//   kq=gid&31 (256 k). Zero barriers in k-loop; G reg-double-buffered.
// bid%3 == 2 -> contrast (512 blocks): cid=bid/3; rt=cid>>4 (256 rows),
//   oct=cid&15 (512 cols); 2 row-sets/wave; 32-col LDS tiles double-buffered.
__global__ __launch_bounds__(256, 2)
void main_fused(const float* __restrict__ G, const float* __restrict__ subx,
                const u16* __restrict__ axG, const u16* __restrict__ axN,
                const float* __restrict__ nsub, const u16* __restrict__ hbf,
                float* __restrict__ spart, float* __restrict__ gpart) {
  __shared__ char clds[2][8192];
  __shared__ float wsum[4];
  int bid = blockIdx.x, tid = threadIdx.x;
  int lane = tid & 63, w = tid >> 6, il = lane & 31, hi = lane >> 5;
  int base = bid / 3, q = bid - base * 3;

  if (q < 2) {
    // ------------------ graph ------------------
    int gid = base * 2 + q;
    int mt = gid >> 5, kq = gid & 31;
    int i = mt * 128 + w * 32 + il;
    const float* gb = G + (size_t)i * 8192 + kq * 256;
    f32x16 acc0 = zero16(), acc1 = zero16(), acc2 = zero16(), acc3 = zero16(), accN = zero16();
    float4 g0[8], g1[8];

    auto loadg = [&](float4* B, int T) {
#pragma unroll
      for (int f = 0; f < 4; ++f) {
        const float* gp = gb + T * 64 + f * 16 + hi * 8;
        B[2 * f]     = *(const float4*)(gp);
        B[2 * f + 1] = *(const float4*)(gp + 4);
      }
    };
    auto consume = [&](const float4* B, int T) {
      int kc0 = kq * 16 + T * 4;
      s16x8 a_[4][4], an_[4];
#pragma unroll
      for (int f = 0; f < 4; ++f) {
        const char* ab = (const char*)axG + (size_t)(kc0 + f) * 4096 + il * 32 + hi * 16;
        a_[f][0] = *(const s16x8*)(ab);
        a_[f][1] = *(const s16x8*)(ab + 1024);
        a_[f][2] = *(const s16x8*)(ab + 2048);
        a_[f][3] = *(const s16x8*)(ab + 3072);
        an_[f]   = *(const s16x8*)((const char*)axN + (size_t)(kc0 + f) * 1024 + il * 32 + hi * 16);
      }
#pragma unroll
      for (int f = 0; f < 4; ++f) {
        s16x8 bb = cvt8(B[2 * f], B[2 * f + 1]);
        acc0 = mfma32(a_[f][0], bb, acc0);
        acc1 = mfma32(a_[f][1], bb, acc1);
        acc2 = mfma32(a_[f][2], bb, acc2);
        acc3 = mfma32(a_[f][3], bb, acc3);
        accN = mfma32(an_[f],  bb, accN);
      }
    };

    loadg(g0, 0);
    loadg(g1, 1);
    consume(g0, 0);
    loadg(g0, 2);
    consume(g1, 1);
    loadg(g1, 3);
    consume(g0, 2);
    consume(g1, 3);

    // epilogue: acc{t32}[r] = y[i][d], d = t32*32 + (r&3) + 8*(r>>2) + 4*hi
    float p = 0.f;
    const float* sxr = subx + (size_t)i * 128;
#pragma unroll
    for (int rq = 0; rq < 4; ++rq) {
      float4 s0 = *(const float4*)(sxr + 0 * 32 + rq * 8 + hi * 4);
      float4 s1 = *(const float4*)(sxr + 1 * 32 + rq * 8 + hi * 4);
      float4 s2 = *(const float4*)(sxr + 2 * 32 + rq * 8 + hi * 4);
      float4 s3 = *(const float4*)(sxr + 3 * 32 + rq * 8 + hi * 4);
      p -= 2.0f * (acc0[rq * 4 + 0] * s0.x + acc0[rq * 4 + 1] * s0.y +
                   acc0[rq * 4 + 2] * s0.z + acc0[rq * 4 + 3] * s0.w +
                   acc1[rq * 4 + 0] * s1.x + acc1[rq * 4 + 1] * s1.y +
                   acc1[rq * 4 + 2] * s1.z + acc1[rq * 4 + 3] * s1.w +
                   acc2[rq * 4 + 0] * s2.x + acc2[rq * 4 + 1] * s2.y +
                   acc2[rq * 4 + 2] * s2.z + acc2[rq * 4 + 3] * s2.w +
                   acc3[rq * 4 + 0] * s3.x + acc3[rq * 4 + 1] * s3.y +
                   acc3[rq * 4 + 2] * s3.z + acc3[rq * 4 + 3] * s3.w);
    }
    if (hi == 0) p += accN[0] + accN[1] * nsub[i];   // row0: t2 partial, row1: rowsum*nsub
#pragma unroll
    for (int d = 1; d < 64; d <<= 1) p += __shfl_xor(p, d, 64);
    if (lane == 0) wsum[w] = p;
    __syncthreads();
    if (tid == 0) gpart[gid] = wsum[0] + wsum[1] + wsum[2] + wsum[3];
  } else {
    // ------------------ contrast ------------------
    int cid = base;
    int rt = cid >> 4, oct = cid & 15;
    int C0 = oct * 512;
    int rowbase = rt * 256 + w * 64;
    s16x8 bf0[8], bf1[8];
#pragma unroll
    for (int rs = 0; rs < 2; ++rs) {
      int r = rowbase + rs * 32 + il;
      const char* rp = (const char*)hbf + (size_t)r * 256;
      int sw = (r & 7) << 4;
#pragma unroll
      for (int ks = 0; ks < 8; ++ks) {
        s16x8 v = *(const s16x8*)(rp + ((ks * 32 + hi * 16) ^ sw));
        if (rs == 0) bf0[ks] = v; else bf1[ks] = v;
      }
    }
    float s0 = 0.f, s1 = 0.f;
    auto stage = [&](int buf, int t) {
      const char* src = (const char*)hbf + (size_t)(C0 + t * 32) * 256 + tid * 16;
      char* dst = &clds[buf][0] + tid * 16;
      gl16(src, dst);
      gl16(src + 4096, dst + 4096);
    };
    stage(0, 0);
    __syncthreads();
    int cur = 0;
    for (int t = 0; t < 16; ++t) {
      if (t < 15) stage(cur ^ 1, t + 1);
      const char* basep = &clds[cur][0];
      s16x8 af[8];
#pragma unroll
      for (int ks = 0; ks < 8; ++ks)
        af[ks] = *(const s16x8*)(basep + il * 256 + ((ks * 32 + hi * 16) ^ ((il & 7) << 4)));
      f32x16 A0 = zero16(), A1 = zero16();
#pragma unroll
      for (int ks = 0; ks < 8; ++ks) {
        A0 = mfma32(af[ks], bf0[ks], A0);
        A1 = mfma32(af[ks], bf1[ks], A1);
      }
      int cb = C0 + t * 32;
      bool d0 = (cb == rowbase), d1 = (cb == rowbase + 32);
#pragma unroll
      for (int r = 0; r < 16; ++r) {
        int jc = (r & 3) + 8 * (r >> 2) + 4 * hi;
        float t0 = fexp2(A0[r] - COFF);
        float t1 = fexp2(A1[r] - COFF);
        if (d0 && jc == il) t0 = 0.f;
        if (d1 && jc == il) t1 = 0.f;
        s0 += t0; s1 += t1;
      }
      __syncthreads();
      cur ^= 1;
    }
    s0 += __shfl_xor(s0, 32, 64);
    s1 += __shfl_xor(s1, 32, 64);
    if (hi == 0) {
      spart[oct * 8192 + rowbase + il]      = s0;
      spart[oct * 8192 + rowbase + 32 + il] = s1;
    }
  }
}

// =================== epilogue: lse + final deterministic sum =================
__global__ __launch_bounds__(1024)
void epilogue(const float* __restrict__ spart, const float* __restrict__ pos4,
              const float* __restrict__ gpart, float* __restrict__ out) {
  int tid = threadIdx.x, lane = tid & 63, w = tid >> 6;
  float csum = 0.f;
#pragma unroll
  for (int rr = 0; rr < 8; ++rr) {
    int row = rr * 1024 + tid;
    float S = 0.f;
#pragma unroll
    for (int o = 0; o < 16; ++o) S += spart[o * 8192 + row];
    csum += LN2F * (COFF + flog2(S)) - pos4[row & 4095];
  }
  double cd = (double)csum;
  double gd = (double)gpart[tid];
#pragma unroll
  for (int d = 1; d < 64; d <<= 1) {
    cd += __shfl_xor(cd, d, 64);
    gd += __shfl_xor(gd, d, 64);
  }
  __shared__ double wc[16], wg[16];
  if (lane == 0) { wc[w] = cd; wg[w] = gd; }
  __syncthreads();
  if (tid == 0) {
    double C = 0.0, Gs = 0.0;
#pragma unroll
    for (int k = 0; k < 16; ++k) { C += wc[k]; Gs += wg[k]; }
    out[0] = (float)(C / 8192.0 + Gs / (4096.0 * 8192.0));
  }
}

extern "C" void kernel_launch(void* const* d_in, const int* in_sizes, int n_in,
                              void* d_out, int out_size, void* d_ws, size_t ws_size,
                              hipStream_t stream) {
  const float* h_i = (const float*)d_in[0];
  const float* h_j = (const float*)d_in[1];
  const float* G   = (const float*)d_in[2];
  const float* sx  = (const float*)d_in[3];
  const float* ax  = (const float*)d_in[4];
  char* ws = (char*)d_ws;
  u16*   hbf   = (u16*)(ws);                    // 2,097,152 B
  u16*   axG   = (u16*)(ws + 2097152);          // 2,097,152 B (512 kc x 4KB)
  u16*   axN   = (u16*)(ws + 4194304);          //   524,288 B (512 kc x 1KB)
  float* nsub  = (float*)(ws + 4718592);        //    16,384 B
  float* pos4  = (float*)(ws + 4734976);        //    16,384 B
  float* spart = (float*)(ws + 4751360);        //   524,288 B (16 x 8192)
  float* gpart = (float*)(ws + 5275648);        //     4,096 B
  float* out = (float*)d_out;

  prep_all<<<dim3(656), dim3(256), 0, stream>>>(h_i, h_j, ax, sx, hbf, axG, axN, nsub, pos4);
  main_fused<<<dim3(1536), dim3(256), 0, stream>>>(G, sx, axG, axN, nsub, hbf, spart, gpart);
  epilogue<<<dim3(1), dim3(1024), 0, stream>>>(spart, pos4, gpart, out);
}